// Round 4
// baseline (144.413 us; speedup 1.0000x reference)
//
#include <hip/hip_runtime.h>

// Gemma3n AltUp, two-kernel split:
//   K1 altup_coefs: per-token RMS-norm + router + tiny 4x4 math -> 20 coefs/token (d_ws)
//   K2 altup_apply: pure elementwise stream, no barriers/reductions.
// Shapes: hidden_states [4, T, H], activated [T, H], w_norm [H],
//         W_router [4, H], W_pred [16, 4], W_corr [4, 4], out [4, T, H]
// T = B*S = 8192, H = 2048, fp32.

constexpr int H = 2048;
constexpr float EPS = 1e-6f;

typedef float f32x4 __attribute__((ext_vector_type(4)));

// ---------------- K1: coefficient kernel ----------------
__global__ __launch_bounds__(512) void altup_coefs(
    const float* __restrict__ hs,       // [4, T, H] (only plane 0 read)
    const float* __restrict__ act,      // [T, H]
    const float* __restrict__ w_norm,   // [H]
    const float* __restrict__ W_router, // [4, H]
    const float* __restrict__ W_pred,   // [16, 4]
    const float* __restrict__ W_corr,   // [4, 4]
    float* __restrict__ coefs)          // [T, 20]: [0..15]=coefT k-major, [16..19]=ccoef
{
    const long long t = blockIdx.x;
    const int tid = threadIdx.x;
    const long long row = t * (long long)H;
    const int h = tid * 4;

    __shared__ float s_red[8][10];

    const f32x4 xa = *reinterpret_cast<const f32x4*>(hs + row + h);
    const f32x4 xc = *reinterpret_cast<const f32x4*>(act + row + h);
    const f32x4 wn = *reinterpret_cast<const f32x4*>(w_norm + h);

    float p[10];
    {
        float s0 = 0.f, s5 = 0.f;
#pragma unroll
        for (int e = 0; e < 4; ++e) { s0 += xa[e] * xa[e]; s5 += xc[e] * xc[e]; }
        p[0] = s0; p[5] = s5;
#pragma unroll
        for (int i = 0; i < 4; ++i) {
            const f32x4 wr4 = *reinterpret_cast<const f32x4*>(W_router + i * H + h);
            float da = 0.f, dc = 0.f;
#pragma unroll
            for (int e = 0; e < 4; ++e) {
                const float wre = wn[e] * wr4[e];
                da += xa[e] * wre;
                dc += xc[e] * wre;
            }
            p[1 + i] = da; p[6 + i] = dc;
        }
    }

#pragma unroll
    for (int m = 1; m < 64; m <<= 1) {
#pragma unroll
        for (int i = 0; i < 10; ++i) p[i] += __shfl_xor(p[i], m, 64);
    }
    const int wave = tid >> 6;
    if ((tid & 63) == 0) {
#pragma unroll
        for (int i = 0; i < 10; ++i) s_red[wave][i] = p[i];
    }
    __syncthreads();
    if (tid != 0) return;

    float tot[10];
#pragma unroll
    for (int i = 0; i < 10; ++i) {
        float s = 0.f;
#pragma unroll
        for (int wv = 0; wv < 8; ++wv) s += s_red[wv][i];
        tot[i] = s;
    }

    const float ris = 1.0f / (float)H;
    const float inv_a = rsqrtf(tot[0] * ris + EPS) * ris;
    const float inv_c = rsqrtf(tot[5] * ris + EPS) * ris;
    float mods[4], modsc[4];
#pragma unroll
    for (int i = 0; i < 4; ++i) {
        mods[i]  = tanhf(tot[1 + i] * inv_a);
        modsc[i] = tanhf(tot[6 + i] * inv_c);
    }
    // coefT[k][j] = sum_m mods[m] * W_pred[(j*4+k)*4 + m]  (swapaxes folded in)
    float cf[20];
#pragma unroll
    for (int k = 0; k < 4; ++k)
#pragma unroll
        for (int j = 0; j < 4; ++j) {
            float s = 0.f;
#pragma unroll
            for (int m = 0; m < 4; ++m) s += mods[m] * W_pred[(j * 4 + k) * 4 + m];
            cf[k * 4 + j] = s;
        }
#pragma unroll
    for (int j = 0; j < 4; ++j) {
        float s = 1.0f;
#pragma unroll
        for (int m = 0; m < 4; ++m) s += modsc[m] * W_corr[j * 4 + m];
        cf[16 + j] = s;
    }
    float* dst = coefs + t * 20;
#pragma unroll
    for (int q = 0; q < 5; ++q) {
        f32x4 v = { cf[q * 4], cf[q * 4 + 1], cf[q * 4 + 2], cf[q * 4 + 3] };
        *reinterpret_cast<f32x4*>(dst + q * 4) = v;
    }
}

// ---------------- K2: streaming apply kernel ----------------
__global__ __launch_bounds__(512) void altup_apply(
    const float* __restrict__ hs,    // [4, T, H]
    const float* __restrict__ act,   // [T, H]
    const float* __restrict__ coefs, // [T, 20]
    float* __restrict__ out,         // [4, T, H]
    long long T)
{
    const long long t = blockIdx.x;
    const int tid = threadIdx.x;
    const long long row = t * (long long)H;
    const long long plane = T * (long long)H;
    const int h = tid * 4;

    // streaming loads first; planes 1-3 non-temporal (read once, don't pollute L3)
    const f32x4 x0 = *reinterpret_cast<const f32x4*>(hs + row + h);
    const f32x4 x1 = __builtin_nontemporal_load(
        reinterpret_cast<const f32x4*>(hs + plane + row + h));
    const f32x4 x2 = __builtin_nontemporal_load(
        reinterpret_cast<const f32x4*>(hs + 2 * plane + row + h));
    const f32x4 x3 = __builtin_nontemporal_load(
        reinterpret_cast<const f32x4*>(hs + 3 * plane + row + h));
    const f32x4 xc = *reinterpret_cast<const f32x4*>(act + row + h);

    // wave-uniform coef loads -> scalar path
    const float* cf = coefs + t * 20;
    float coefT[16], ccoef[4];
#pragma unroll
    for (int i = 0; i < 16; ++i) coefT[i] = cf[i];
#pragma unroll
    for (int j = 0; j < 4; ++j) ccoef[j] = cf[16 + j];

    f32x4 o4[4];
#pragma unroll
    for (int e = 0; e < 4; ++e) {
        const float xk[4] = { x0[e], x1[e], x2[e], x3[e] };
        float pred[4];
#pragma unroll
        for (int j = 0; j < 4; ++j) {
            float s = xk[j]; // residual
#pragma unroll
            for (int k = 0; k < 4; ++k) s += xk[k] * coefT[k * 4 + j];
            pred[j] = s;
        }
        const float innov = xc[e] - pred[0];
#pragma unroll
        for (int j = 0; j < 4; ++j)
            o4[j][e] = pred[j] + innov * ccoef[j];
    }
#pragma unroll
    for (int j = 0; j < 4; ++j)
        __builtin_nontemporal_store(o4[j],
            reinterpret_cast<f32x4*>(out + j * plane + row + h));
}

// ---------------- fallback: single fused kernel (ws too small) ----------------
__global__ __launch_bounds__(512) void altup_fused(
    const float* __restrict__ hs, const float* __restrict__ act,
    const float* __restrict__ w_norm, const float* __restrict__ W_router,
    const float* __restrict__ W_pred, const float* __restrict__ W_corr,
    float* __restrict__ out, long long T)
{
    const long long t = blockIdx.x;
    const int tid = threadIdx.x;
    const long long row = t * (long long)H;
    const long long plane = T * (long long)H;
    const int h = tid * 4;
    __shared__ float s_red[8][10];

    const f32x4 x0 = *reinterpret_cast<const f32x4*>(hs + row + h);
    const f32x4 x1 = *reinterpret_cast<const f32x4*>(hs + plane + row + h);
    const f32x4 x2 = *reinterpret_cast<const f32x4*>(hs + 2 * plane + row + h);
    const f32x4 x3 = *reinterpret_cast<const f32x4*>(hs + 3 * plane + row + h);
    const f32x4 xc = *reinterpret_cast<const f32x4*>(act + row + h);
    const f32x4 wn = *reinterpret_cast<const f32x4*>(w_norm + h);

    float p[10];
    {
        float s0 = 0.f, s5 = 0.f;
#pragma unroll
        for (int e = 0; e < 4; ++e) { s0 += x0[e]*x0[e]; s5 += xc[e]*xc[e]; }
        p[0] = s0; p[5] = s5;
#pragma unroll
        for (int i = 0; i < 4; ++i) {
            const f32x4 wr4 = *reinterpret_cast<const f32x4*>(W_router + i * H + h);
            float da = 0.f, dc = 0.f;
#pragma unroll
            for (int e = 0; e < 4; ++e) { const float wre = wn[e]*wr4[e]; da += x0[e]*wre; dc += xc[e]*wre; }
            p[1+i] = da; p[6+i] = dc;
        }
    }
#pragma unroll
    for (int m = 1; m < 64; m <<= 1) {
#pragma unroll
        for (int i = 0; i < 10; ++i) p[i] += __shfl_xor(p[i], m, 64);
    }
    const int wave = tid >> 6;
    if ((tid & 63) == 0) {
#pragma unroll
        for (int i = 0; i < 10; ++i) s_red[wave][i] = p[i];
    }
    __syncthreads();
    float tot[10];
#pragma unroll
    for (int i = 0; i < 10; ++i) {
        float s = 0.f;
#pragma unroll
        for (int wv = 0; wv < 8; ++wv) s += s_red[wv][i];
        tot[i] = s;
    }
    const float ris = 1.0f / (float)H;
    const float inv_a = rsqrtf(tot[0] * ris + EPS) * ris;
    const float inv_c = rsqrtf(tot[5] * ris + EPS) * ris;
    float mods[4], modsc[4];
#pragma unroll
    for (int i = 0; i < 4; ++i) { mods[i] = tanhf(tot[1+i]*inv_a); modsc[i] = tanhf(tot[6+i]*inv_c); }
    float coefT[4][4];
#pragma unroll
    for (int j = 0; j < 4; ++j)
#pragma unroll
        for (int k = 0; k < 4; ++k) {
            float s = 0.f;
#pragma unroll
            for (int m = 0; m < 4; ++m) s += mods[m] * W_pred[(j*4+k)*4 + m];
            coefT[k][j] = s;
        }
    float ccoef[4];
#pragma unroll
    for (int j = 0; j < 4; ++j) {
        float s = 1.0f;
#pragma unroll
        for (int m = 0; m < 4; ++m) s += modsc[m] * W_corr[j*4 + m];
        ccoef[j] = s;
    }
    f32x4 o4[4];
#pragma unroll
    for (int e = 0; e < 4; ++e) {
        const float xk[4] = { x0[e], x1[e], x2[e], x3[e] };
        float pred[4];
#pragma unroll
        for (int j = 0; j < 4; ++j) {
            float s = xk[j];
#pragma unroll
            for (int k = 0; k < 4; ++k) s += xk[k] * coefT[k][j];
            pred[j] = s;
        }
        const float innov = xc[e] - pred[0];
#pragma unroll
        for (int j = 0; j < 4; ++j) o4[j][e] = pred[j] + innov * ccoef[j];
    }
#pragma unroll
    for (int j = 0; j < 4; ++j)
        *reinterpret_cast<f32x4*>(out + j * plane + row + h) = o4[j];
}

extern "C" void kernel_launch(void* const* d_in, const int* in_sizes, int n_in,
                              void* d_out, int out_size, void* d_ws, size_t ws_size,
                              hipStream_t stream) {
    const float* hs       = (const float*)d_in[0];
    const float* act      = (const float*)d_in[1];
    const float* w_norm   = (const float*)d_in[2];
    const float* W_router = (const float*)d_in[3];
    const float* W_pred   = (const float*)d_in[4];
    const float* W_corr   = (const float*)d_in[5];
    float* out = (float*)d_out;
    const long long T = (long long)in_sizes[0] / (4LL * H); // B*S

    const size_t need = (size_t)T * 20 * sizeof(float);
    if (ws_size >= need) {
        float* coefs = (float*)d_ws;
        altup_coefs<<<dim3((unsigned)T), dim3(512), 0, stream>>>(
            hs, act, w_norm, W_router, W_pred, W_corr, coefs);
        altup_apply<<<dim3((unsigned)T), dim3(512), 0, stream>>>(
            hs, act, coefs, out, T);
    } else {
        altup_fused<<<dim3((unsigned)T), dim3(512), 0, stream>>>(
            hs, act, w_norm, W_router, W_pred, W_corr, out, T);
    }
}

// Round 5
// 140.222 us; speedup vs baseline: 1.0299x; 1.0299x over previous
//
#include <hip/hip_runtime.h>

// Gemma3n AltUp fused, R5: single kernel, grid-stride software pipeline.
// Shapes: hidden_states [4, T, H], activated [T, H], w_norm [H],
//         W_router [4, H], W_pred [16, 4], W_corr [4, 4], out [4, T, H]
// T = B*S = 8192, H = 2048, fp32. ~604 MB HBM traffic, floor ~96 us.
//
// Structure: 512 thr/block (1 float4 per lane covers H=2048), each block
// processes ITERS tokens with stride gridDim.x. Next token's 5 streaming
// loads are issued BEFORE the current token's reduce, so HBM latency hides
// under the shfl chain + barrier. s_red is ping-ponged so one barrier/token
// suffices. All streaming accesses nontemporal (touch-once data).

constexpr int H = 2048;
constexpr float EPS = 1e-6f;

typedef float f32x4 __attribute__((ext_vector_type(4)));

__device__ __forceinline__ f32x4 nt_load(const float* p) {
    return __builtin_nontemporal_load(reinterpret_cast<const f32x4*>(p));
}
__device__ __forceinline__ void nt_store(float* p, f32x4 v) {
    __builtin_nontemporal_store(v, reinterpret_cast<f32x4*>(p));
}

__global__ __launch_bounds__(512) void altup_fused(
    const float* __restrict__ hs,       // [4, T, H]
    const float* __restrict__ act,      // [T, H]
    const float* __restrict__ w_norm,   // [H]
    const float* __restrict__ W_router, // [4, H]
    const float* __restrict__ W_pred,   // [16, 4]
    const float* __restrict__ W_corr,   // [4, 4]
    float* __restrict__ out,            // [4, T, H]
    long long T, int iters)
{
    const int tid = threadIdx.x;
    const int h = tid * 4;
    const long long plane = T * (long long)H;
    const long long strideT = gridDim.x;

    __shared__ float s_red[2][8][10];

    // ---- token-invariant operands (hoisted) ----
    const f32x4 wn = *reinterpret_cast<const f32x4*>(w_norm + h);
    f32x4 wrw[4];
#pragma unroll
    for (int i = 0; i < 4; ++i) {
        const f32x4 wr = *reinterpret_cast<const f32x4*>(W_router + i * H + h);
#pragma unroll
        for (int e = 0; e < 4; ++e) wrw[i][e] = wn[e] * wr[e];
    }

    long long t = blockIdx.x;

    // ---- prologue: first token's streaming loads ----
    f32x4 cx0 = nt_load(hs + t * H + h);
    f32x4 cx1 = nt_load(hs + plane + t * H + h);
    f32x4 cx2 = nt_load(hs + 2 * plane + t * H + h);
    f32x4 cx3 = nt_load(hs + 3 * plane + t * H + h);
    f32x4 cxc = nt_load(act + t * H + h);

    for (int it = 0; it < iters; ++it) {
        // ---- issue NEXT token's loads before the reduce ----
        const long long tn = t + strideT;
        f32x4 nx0, nx1, nx2, nx3, nxc;
        if (it + 1 < iters) {
            nx0 = nt_load(hs + tn * H + h);
            nx1 = nt_load(hs + plane + tn * H + h);
            nx2 = nt_load(hs + 2 * plane + tn * H + h);
            nx3 = nt_load(hs + 3 * plane + tn * H + h);
            nxc = nt_load(act + tn * H + h);
        }

        // ---- partials ----
        float p[10];
        {
            float s0 = 0.f, s5 = 0.f;
#pragma unroll
            for (int e = 0; e < 4; ++e) { s0 += cx0[e] * cx0[e]; s5 += cxc[e] * cxc[e]; }
            p[0] = s0; p[5] = s5;
#pragma unroll
            for (int i = 0; i < 4; ++i) {
                float da = 0.f, dc = 0.f;
#pragma unroll
                for (int e = 0; e < 4; ++e) {
                    da += cx0[e] * wrw[i][e];
                    dc += cxc[e] * wrw[i][e];
                }
                p[1 + i] = da; p[6 + i] = dc;
            }
        }

        // ---- wave butterfly + single-barrier cross-wave reduce (ping-pong) ----
#pragma unroll
        for (int m = 1; m < 64; m <<= 1) {
#pragma unroll
            for (int i = 0; i < 10; ++i) p[i] += __shfl_xor(p[i], m, 64);
        }
        const int buf = it & 1;
        const int wave = tid >> 6;
        if ((tid & 63) == 0) {
#pragma unroll
            for (int i = 0; i < 10; ++i) s_red[buf][wave][i] = p[i];
        }
        __syncthreads();

        float tot[10];
#pragma unroll
        for (int i = 0; i < 10; ++i) {
            float s = 0.f;
#pragma unroll
            for (int wv = 0; wv < 8; ++wv) s += s_red[buf][wv][i];
            tot[i] = s;
        }

        // ---- coefficient math (redundant per thread; scalar broadcasts) ----
        const float ris = 1.0f / (float)H;
        const float inv_a = rsqrtf(tot[0] * ris + EPS) * ris;
        const float inv_c = rsqrtf(tot[5] * ris + EPS) * ris;
        float mods[4], modsc[4];
#pragma unroll
        for (int i = 0; i < 4; ++i) {
            mods[i]  = tanhf(tot[1 + i] * inv_a);
            modsc[i] = tanhf(tot[6 + i] * inv_c);
        }
        // coefT[k][j] = sum_m mods[m] * W_pred[(j*4+k)*4 + m]  (swapaxes folded)
        float coefT[4][4];
#pragma unroll
        for (int j = 0; j < 4; ++j)
#pragma unroll
            for (int k = 0; k < 4; ++k) {
                float s = 0.f;
#pragma unroll
                for (int m = 0; m < 4; ++m) s += mods[m] * W_pred[(j * 4 + k) * 4 + m];
                coefT[k][j] = s;
            }
        float ccoef[4];
#pragma unroll
        for (int j = 0; j < 4; ++j) {
            float s = 1.0f;
#pragma unroll
            for (int m = 0; m < 4; ++m) s += modsc[m] * W_corr[j * 4 + m];
            ccoef[j] = s;
        }

        // ---- outputs ----
        f32x4 o4[4];
#pragma unroll
        for (int e = 0; e < 4; ++e) {
            const float xk[4] = { cx0[e], cx1[e], cx2[e], cx3[e] };
            float pred[4];
#pragma unroll
            for (int j = 0; j < 4; ++j) {
                float s = xk[j]; // residual
#pragma unroll
                for (int k = 0; k < 4; ++k) s += xk[k] * coefT[k][j];
                pred[j] = s;
            }
            const float innov = cxc[e] - pred[0];
#pragma unroll
            for (int j = 0; j < 4; ++j)
                o4[j][e] = pred[j] + innov * ccoef[j];
        }
#pragma unroll
        for (int j = 0; j < 4; ++j)
            nt_store(out + j * plane + t * H + h, o4[j]);

        // ---- rotate pipeline ----
        t = tn;
        cx0 = nx0; cx1 = nx1; cx2 = nx2; cx3 = nx3; cxc = nxc;
    }
}

extern "C" void kernel_launch(void* const* d_in, const int* in_sizes, int n_in,
                              void* d_out, int out_size, void* d_ws, size_t ws_size,
                              hipStream_t stream) {
    const float* hs       = (const float*)d_in[0];
    const float* act      = (const float*)d_in[1];
    const float* w_norm   = (const float*)d_in[2];
    const float* W_router = (const float*)d_in[3];
    const float* W_pred   = (const float*)d_in[4];
    const float* W_corr   = (const float*)d_in[5];
    float* out = (float*)d_out;
    const long long T = (long long)in_sizes[0] / (4LL * H); // B*S

    int iters = 4;
    if (T % iters != 0) iters = 1;
    const unsigned grid = (unsigned)(T / iters);
    altup_fused<<<dim3(grid), dim3(512), 0, stream>>>(
        hs, act, w_norm, W_router, W_pred, W_corr, out, T, iters);
}